// Round 4
// baseline (1155.157 us; speedup 1.0000x reference)
//
#include <hip/hip_runtime.h>

// Problem constants (from reference)
#define BATCH 2048
#define T 512
#define NF 10
#define HID 30
#define S3T 1536          // 3*T sequence length after reshape/transpose
#define FEAT_PER_B 15360  // T*30 floats per batch element
// Workspace: BATCH * FEAT_PER_B * 4 = 125,829,120 bytes (fp32 feat)

__device__ __forceinline__ float fexp(float x) {
    return __builtin_amdgcn_exp2f(x * 1.44269504088896f);  // v_exp_f32
}
__device__ __forceinline__ float frcp(float x) {
    return __builtin_amdgcn_rcpf(x);                        // v_rcp_f32
}
__device__ __forceinline__ float sigmoid_(float x) {
    return frcp(1.0f + fexp(-x));
}
__device__ __forceinline__ float tanh_(float x) {
    return 2.0f * frcp(1.0f + fexp(-2.0f * x)) - 1.0f;
}

// Pin a value into a VGPR: opaque to the optimizer, so the register allocator
// can NOT rematerialize the originating load inside the loop. (R2/R3 evidence:
// VGPR_Count 116/52 < live state -> LLVM was re-loading weights every step.)
#define PIN(x) asm volatile("" : "+v"(x))

// Kernel 1: materialize featflat[b][t*30+c] = concat(e_i, e_j, rbf)
__global__ void feat_kernel(const int* __restrict__ atom_i,
                            const int* __restrict__ atom_j,
                            const float* __restrict__ dist,
                            const float* __restrict__ emb,
                            float* __restrict__ feat) {
    int gid = blockIdx.x * blockDim.x + threadIdx.x;
    const int total = BATCH * FEAT_PER_B;
    if (gid >= total) return;
    int b = gid / FEAT_PER_B;
    int r = gid - b * FEAT_PER_B;
    int t = r / 30;
    int c = r - t * 30;
    int bt = b * T + t;
    float v;
    if (c < 10) {
        int ai = atom_i[bt];
        v = (ai != 0) ? emb[ai * NF + c] : 0.0f;
    } else if (c < 20) {
        int aj = atom_j[bt];
        v = (aj != 0) ? emb[aj * NF + (c - 10)] : 0.0f;
    } else {
        int ai = atom_i[bt];
        float d = dist[bt];
        float ctr = (float)(c - 19) * 0.7f;
        float diff = ctr - d;
        v = (ai != 0) ? fexp(-diff * diff) : 0.0f;
    }
    feat[gid] = v;
}

// Kernel 2: GRU recurrence. One wave per block, one batch element per wave.
// Lane pair (k, k+32) shares hidden unit k: half p accumulates 15 of the 30
// hh terms and 5 of the 10 ih terms; one shfl_xor(32) combines.
// __launch_bounds__(64,2): VGPR cap 256 (grid gives 2 waves/SIMD anyway).
__launch_bounds__(64, 2)
__global__ void gru_kernel(const float* __restrict__ feat,
                           const float* __restrict__ W_ih,   // [90,10]
                           const float* __restrict__ W_hh,   // [90,30]
                           const float* __restrict__ b_ih,   // [90]
                           const float* __restrict__ b_hh,   // [90]
                           const float* __restrict__ W_out,  // [1,30]
                           const float* __restrict__ b_out,  // [1]
                           float* __restrict__ out) {
    // Double-buffered h, halves padded to 16 floats for aligned b128 reads.
    __shared__ __align__(16) float hbuf[2][32];
    const int lane = threadIdx.x;
    const int p = lane >> 5;           // which half of the reduction
    const int k = lane & 31;           // hidden unit
    const bool active = (k < HID);
    const int kk = active ? k : (HID - 1);
    const int b = blockIdx.x;
    const int j0 = p * 15;             // my hh column range
    const int d0 = p * 5;              // my ih column range

    // Per-lane weights: 45 hh + 15 ih = 60 VGPRs, pinned.
    float whh_r[15], whh_z[15], whh_n[15];
#pragma unroll
    for (int jj = 0; jj < 15; ++jj) {
        int j = j0 + jj;
        whh_r[jj] = W_hh[(0 * HID + kk) * HID + j];
        whh_z[jj] = W_hh[(1 * HID + kk) * HID + j];
        whh_n[jj] = W_hh[(2 * HID + kk) * HID + j];
        PIN(whh_r[jj]); PIN(whh_z[jj]); PIN(whh_n[jj]);
    }
    float wih_r[5], wih_z[5], wih_n[5];
#pragma unroll
    for (int dd = 0; dd < 5; ++dd) {
        int d = d0 + dd;
        wih_r[dd] = W_ih[(0 * HID + kk) * NF + d];
        wih_z[dd] = W_ih[(1 * HID + kk) * NF + d];
        wih_n[dd] = W_ih[(2 * HID + kk) * NF + d];
        PIN(wih_r[dd]); PIN(wih_z[dd]); PIN(wih_n[dd]);
    }
    float brz_r = b_ih[0 * HID + kk] + b_hh[0 * HID + kk];
    float brz_z = b_ih[1 * HID + kk] + b_hh[1 * HID + kk];
    float bi_n  = b_ih[2 * HID + kk];  // n-gate biases stay split:
    float bh_n  = b_hh[2 * HID + kk];  // n = tanh(i_n + r*(hh_n + b_hh_n))
    PIN(brz_r); PIN(brz_z); PIN(bi_n); PIN(bh_n);

    const float* xp = feat + (long)b * FEAT_PER_B + (long)d0 * S3T;

    hbuf[0][lane & 31] = 0.0f;  // zero step-0 read buffer (incl. pad slots)
    __syncthreads();

    float h = 0.0f;
    // 2-deep x prefetch ring (x partially HBM-resident: FETCH=63MB of 126MB)
    float xc[5], x1[5];
#pragma unroll
    for (int dd = 0; dd < 5; ++dd) xc[dd] = xp[dd * S3T + 0];
#pragma unroll
    for (int dd = 0; dd < 5; ++dd) x1[dd] = xp[dd * S3T + 1];

#pragma unroll 1
    for (int s = 0; s < S3T; ++s) {
        float* rb = hbuf[s & 1];
        float* wb = hbuf[(s + 1) & 1];

        // Prefetch x for step s+2
        float x2[5];
        const int sn = (s + 2 < S3T) ? (s + 2) : s;
#pragma unroll
        for (int dd = 0; dd < 5; ++dd) x2[dd] = xp[dd * S3T + sn];

        // h broadcast: 4 x ds_read_b128 (16 floats, 15 used)
        const float4* hv = (const float4*)&rb[p * 16];
        float hj[16];
        *(float4*)&hj[0]  = hv[0];
        *(float4*)&hj[4]  = hv[1];
        *(float4*)&hj[8]  = hv[2];
        *(float4*)&hj[12] = hv[3];

        float ar = 0.0f, az = 0.0f, ani = 0.0f, anh = 0.0f;
#pragma unroll
        for (int dd = 0; dd < 5; ++dd) {
            ar  += wih_r[dd] * xc[dd];
            az  += wih_z[dd] * xc[dd];
            ani += wih_n[dd] * xc[dd];
        }
#pragma unroll
        for (int jj = 0; jj < 15; ++jj) {
            ar  += whh_r[jj] * hj[jj];
            az  += whh_z[jj] * hj[jj];
            anh += whh_n[jj] * hj[jj];
        }
        // combine lane-pair halves (biases added once, after the reduce)
        ar  += __shfl_xor(ar, 32, 64);
        az  += __shfl_xor(az, 32, 64);
        ani += __shfl_xor(ani, 32, 64);
        anh += __shfl_xor(anh, 32, 64);

        float rg = sigmoid_(ar + brz_r);
        float zg = sigmoid_(az + brz_z);
        float ng = tanh_(ani + bi_n + rg * (anh + bh_n));
        h = ng + zg * (h - ng);  // (1-z)*n + z*h

        if (p == 0 && active) wb[(k < 15) ? k : (k + 1)] = h;
        __syncthreads();  // write visible before next step's reads; also
                          // drains this step's rb reads before wb reuse

#pragma unroll
        for (int dd = 0; dd < 5; ++dd) { xc[dd] = x1[dd]; x1[dd] = x2[dd]; }
    }

    // out[b] = relu(h . W_out + b_out); only p==0,k<30 lanes contribute
    float prod = h * (active ? W_out[kk] : 0.0f);
    float v = (p == 0 && active) ? prod : 0.0f;
#pragma unroll
    for (int off = 32; off; off >>= 1) v += __shfl_xor(v, off, 64);
    if (lane == 0) {
        float o = v + b_out[0];
        out[b] = o > 0.0f ? o : 0.0f;
    }
}

extern "C" void kernel_launch(void* const* d_in, const int* in_sizes, int n_in,
                              void* d_out, int out_size, void* d_ws, size_t ws_size,
                              hipStream_t stream) {
    const int* atom_i   = (const int*)d_in[0];
    const int* atom_j   = (const int*)d_in[1];
    const float* dist   = (const float*)d_in[2];
    const float* emb    = (const float*)d_in[3];
    const float* W_ih   = (const float*)d_in[4];
    const float* W_hh   = (const float*)d_in[5];
    const float* b_ih   = (const float*)d_in[6];
    const float* b_hh   = (const float*)d_in[7];
    const float* W_out  = (const float*)d_in[8];
    const float* b_out  = (const float*)d_in[9];
    float* out = (float*)d_out;
    float* feat = (float*)d_ws;

    const int total = BATCH * FEAT_PER_B;
    const int threads = 256;
    const int blocks = (total + threads - 1) / threads;
    feat_kernel<<<blocks, threads, 0, stream>>>(atom_i, atom_j, dist, emb, feat);
    gru_kernel<<<BATCH, 64, 0, stream>>>(feat, W_ih, W_hh, b_ih, b_hh,
                                         W_out, b_out, out);
}

// Round 5
// 1024.307 us; speedup vs baseline: 1.1277x; 1.1277x over previous
//
#include <hip/hip_runtime.h>

// Problem constants (from reference)
#define BATCH 2048
#define T 512
#define NF 10
#define HID 30
#define S3T 1536          // 3*T sequence length after reshape/transpose
#define FEAT_PER_B 15360  // T*30 floats per batch element
// Workspace: BATCH * FEAT_PER_B * 4 = 125,829,120 bytes (fp32 feat)

__device__ __forceinline__ float fexp(float x) {
    return __builtin_amdgcn_exp2f(x * 1.44269504088896f);  // v_exp_f32
}
__device__ __forceinline__ float frcp(float x) {
    return __builtin_amdgcn_rcpf(x);                        // v_rcp_f32
}
__device__ __forceinline__ float sigmoid_(float x) {
    return frcp(1.0f + fexp(-x));
}
__device__ __forceinline__ float tanh_(float x) {
    return 2.0f * frcp(1.0f + fexp(-2.0f * x)) - 1.0f;
}

// Kernel 1: materialize featflat[b][t*30+c] = concat(e_i, e_j, rbf)
__global__ void feat_kernel(const int* __restrict__ atom_i,
                            const int* __restrict__ atom_j,
                            const float* __restrict__ dist,
                            const float* __restrict__ emb,
                            float* __restrict__ feat) {
    int gid = blockIdx.x * blockDim.x + threadIdx.x;
    const int total = BATCH * FEAT_PER_B;
    if (gid >= total) return;
    int b = gid / FEAT_PER_B;
    int r = gid - b * FEAT_PER_B;
    int t = r / 30;
    int c = r - t * 30;
    int bt = b * T + t;
    float v;
    if (c < 10) {
        int ai = atom_i[bt];
        v = (ai != 0) ? emb[ai * NF + c] : 0.0f;
    } else if (c < 20) {
        int aj = atom_j[bt];
        v = (aj != 0) ? emb[aj * NF + (c - 10)] : 0.0f;
    } else {
        int ai = atom_i[bt];
        float d = dist[bt];
        float ctr = (float)(c - 19) * 0.7f;
        float diff = ctr - d;
        v = (ai != 0) ? fexp(-diff * diff) : 0.0f;
    }
    feat[gid] = v;
}

// Kernel 2: GRU recurrence. One wave per block, one batch element per wave.
// Lane pair (k, k+32) shares hidden unit k: half p accumulates 15 of the 30
// hh terms and 5 of the 10 ih terms; one shfl_xor(32) combines.
//
// __launch_bounds__(64,1): min-waves/EU=1 -> 512-reg allocator budget.
// R2/R3/R4 counter evidence: with tighter bounds ((64,4)->VGPR=52,
// (64,2)->VGPR=56) LLVM parks the weight arrays in AGPRs and pays one
// v_accvgpr_read per use per step (~2x VALU instrs); with (64,1) R2 got
// VGPR=116 (resident). Runtime occupancy is unchanged: ~112 VGPRs still
// admits 4 waves/SIMD, and the 2048-wave grid supplies only 2/SIMD.
__launch_bounds__(64, 1)
__global__ void gru_kernel(const float* __restrict__ feat,
                           const float* __restrict__ W_ih,   // [90,10]
                           const float* __restrict__ W_hh,   // [90,30]
                           const float* __restrict__ b_ih,   // [90]
                           const float* __restrict__ b_hh,   // [90]
                           const float* __restrict__ W_out,  // [1,30]
                           const float* __restrict__ b_out,  // [1]
                           float* __restrict__ out) {
    // Double-buffered h, halves padded to 16 floats for aligned b128 reads.
    __shared__ __align__(16) float hbuf[2][32];
    const int lane = threadIdx.x;
    const int p = lane >> 5;           // which half of the reduction
    const int k = lane & 31;           // hidden unit
    const bool active = (k < HID);
    const int kk = active ? k : (HID - 1);
    const int b = blockIdx.x;
    const int j0 = p * 15;             // my hh column range
    const int d0 = p * 5;              // my ih column range

    // Per-lane weights: 45 hh + 15 ih = 60 VGPRs
    float whh_r[15], whh_z[15], whh_n[15];
#pragma unroll
    for (int jj = 0; jj < 15; ++jj) {
        int j = j0 + jj;
        whh_r[jj] = W_hh[(0 * HID + kk) * HID + j];
        whh_z[jj] = W_hh[(1 * HID + kk) * HID + j];
        whh_n[jj] = W_hh[(2 * HID + kk) * HID + j];
    }
    float wih_r[5], wih_z[5], wih_n[5];
#pragma unroll
    for (int dd = 0; dd < 5; ++dd) {
        int d = d0 + dd;
        wih_r[dd] = W_ih[(0 * HID + kk) * NF + d];
        wih_z[dd] = W_ih[(1 * HID + kk) * NF + d];
        wih_n[dd] = W_ih[(2 * HID + kk) * NF + d];
    }
    const float brz_r = b_ih[0 * HID + kk] + b_hh[0 * HID + kk];
    const float brz_z = b_ih[1 * HID + kk] + b_hh[1 * HID + kk];
    const float bi_n  = b_ih[2 * HID + kk];  // n-gate biases stay split:
    const float bh_n  = b_hh[2 * HID + kk];  // n = tanh(i_n + r*(hh_n + b_hh_n))

    const float* xp = feat + (long)b * FEAT_PER_B + (long)d0 * S3T;

    hbuf[0][lane & 31] = 0.0f;  // zero step-0 read buffer (incl. pad slots)
    __syncthreads();

    float h = 0.0f;
    float xc[5];
#pragma unroll
    for (int dd = 0; dd < 5; ++dd) xc[dd] = xp[dd * S3T];

#pragma unroll 2
    for (int s = 0; s < S3T; ++s) {
        float* rb = hbuf[s & 1];
        float* wb = hbuf[(s + 1) & 1];

        // Prefetch next step's x (stride 6144 B, LLC-resident)
        float xn[5];
        const int sn = (s + 1 < S3T) ? (s + 1) : s;
#pragma unroll
        for (int dd = 0; dd < 5; ++dd) xn[dd] = xp[dd * S3T + sn];

        // h broadcast: 4 x ds_read_b128 (16 floats, 15 used)
        const float4* hv = (const float4*)&rb[p * 16];
        float hj[16];
        *(float4*)&hj[0]  = hv[0];
        *(float4*)&hj[4]  = hv[1];
        *(float4*)&hj[8]  = hv[2];
        *(float4*)&hj[12] = hv[3];

        float ar = 0.0f, az = 0.0f, ani = 0.0f, anh = 0.0f;
#pragma unroll
        for (int dd = 0; dd < 5; ++dd) {
            ar  += wih_r[dd] * xc[dd];
            az  += wih_z[dd] * xc[dd];
            ani += wih_n[dd] * xc[dd];
        }
#pragma unroll
        for (int jj = 0; jj < 15; ++jj) {
            ar  += whh_r[jj] * hj[jj];
            az  += whh_z[jj] * hj[jj];
            anh += whh_n[jj] * hj[jj];
        }
        // combine lane-pair halves (biases added once, after the reduce)
        ar  += __shfl_xor(ar, 32, 64);
        az  += __shfl_xor(az, 32, 64);
        ani += __shfl_xor(ani, 32, 64);
        anh += __shfl_xor(anh, 32, 64);

        float rg = sigmoid_(ar + brz_r);
        float zg = sigmoid_(az + brz_z);
        float ng = tanh_(ani + bi_n + rg * (anh + bh_n));
        h = ng + zg * (h - ng);  // (1-z)*n + z*h

        if (p == 0 && active) wb[(k < 15) ? k : (k + 1)] = h;
        __syncthreads();  // write visible before next step's reads; also
                          // drains this step's rb reads before wb reuse

#pragma unroll
        for (int dd = 0; dd < 5; ++dd) xc[dd] = xn[dd];
    }

    // out[b] = relu(h . W_out + b_out); only p==0,k<30 lanes contribute
    float prod = h * (active ? W_out[kk] : 0.0f);
    float v = (p == 0 && active) ? prod : 0.0f;
#pragma unroll
    for (int off = 32; off; off >>= 1) v += __shfl_xor(v, off, 64);
    if (lane == 0) {
        float o = v + b_out[0];
        out[b] = o > 0.0f ? o : 0.0f;
    }
}

extern "C" void kernel_launch(void* const* d_in, const int* in_sizes, int n_in,
                              void* d_out, int out_size, void* d_ws, size_t ws_size,
                              hipStream_t stream) {
    const int* atom_i   = (const int*)d_in[0];
    const int* atom_j   = (const int*)d_in[1];
    const float* dist   = (const float*)d_in[2];
    const float* emb    = (const float*)d_in[3];
    const float* W_ih   = (const float*)d_in[4];
    const float* W_hh   = (const float*)d_in[5];
    const float* b_ih   = (const float*)d_in[6];
    const float* b_hh   = (const float*)d_in[7];
    const float* W_out  = (const float*)d_in[8];
    const float* b_out  = (const float*)d_in[9];
    float* out = (float*)d_out;
    float* feat = (float*)d_ws;

    const int total = BATCH * FEAT_PER_B;
    const int threads = 256;
    const int blocks = (total + threads - 1) / threads;
    feat_kernel<<<blocks, threads, 0, stream>>>(atom_i, atom_j, dist, emb, feat);
    gru_kernel<<<BATCH, 64, 0, stream>>>(feat, W_ih, W_hh, b_ih, b_hh,
                                         W_out, b_out, out);
}

// Round 6
// 826.326 us; speedup vs baseline: 1.3979x; 1.2396x over previous
//
#include <hip/hip_runtime.h>

// Problem constants (from reference)
#define BATCH 2048
#define T 512
#define NF 10
#define HID 30
#define S3T 1536          // 3*T sequence length after reshape/transpose
#define FEAT_PER_B 15360  // T*30 floats per batch element
// Workspace: BATCH * FEAT_PER_B * 4 = 125,829,120 bytes (fp32 feat)

__device__ __forceinline__ float fexp(float x) {
    return __builtin_amdgcn_exp2f(x * 1.44269504088896f);  // v_exp_f32
}
__device__ __forceinline__ float frcp(float x) {
    return __builtin_amdgcn_rcpf(x);                        // v_rcp_f32
}
__device__ __forceinline__ float sigmoid_(float x) {
    return frcp(1.0f + fexp(-x));
}
__device__ __forceinline__ float tanh_(float x) {
    return 2.0f * frcp(1.0f + fexp(-2.0f * x)) - 1.0f;
}

// Kernel 1: materialize featflat[b][t*30+c] = concat(e_i, e_j, rbf)
__global__ void feat_kernel(const int* __restrict__ atom_i,
                            const int* __restrict__ atom_j,
                            const float* __restrict__ dist,
                            const float* __restrict__ emb,
                            float* __restrict__ feat) {
    int gid = blockIdx.x * blockDim.x + threadIdx.x;
    const int total = BATCH * FEAT_PER_B;
    if (gid >= total) return;
    int b = gid / FEAT_PER_B;
    int r = gid - b * FEAT_PER_B;
    int t = r / 30;
    int c = r - t * 30;
    int bt = b * T + t;
    float v;
    if (c < 10) {
        int ai = atom_i[bt];
        v = (ai != 0) ? emb[ai * NF + c] : 0.0f;
    } else if (c < 20) {
        int aj = atom_j[bt];
        v = (aj != 0) ? emb[aj * NF + (c - 10)] : 0.0f;
    } else {
        int ai = atom_i[bt];
        float d = dist[bt];
        float ctr = (float)(c - 19) * 0.7f;
        float diff = ctr - d;
        v = (ai != 0) ? fexp(-diff * diff) : 0.0f;
    }
    feat[gid] = v;
}

// Kernel 2: GRU recurrence. One wave per block, one batch element per wave.
// Lane pair (k, k+32) shares hidden unit k: half p accumulates 15 of the 30
// hh terms and 5 of the 10 ih terms; one shfl_xor(32) combines.
//
// R3/R4/R5 counter evidence: __launch_bounds__ 2nd arg only CAPS the register
// budget (min waves/EU); the GCN scheduler still minimizes pressure toward
// MAX occupancy (8 waves/SIMD -> 52 arch VGPRs) and evicts the ~110 live
// weights (AGPR park / reload), costing ~+133 VALU instr/step (measured 228
// vs ~95 hand-counted). Our grid supplies only 2 waves/SIMD, so that shrink
// buys nothing. amdgpu_waves_per_eu(2,2) sets the occupancy CEILING -> the
// scheduler's pressure target becomes 256 regs -> weights stay arch-resident.
__attribute__((amdgpu_waves_per_eu(2, 2)))
__global__ void __launch_bounds__(64)
gru_kernel(const float* __restrict__ feat,
           const float* __restrict__ W_ih,   // [90,10]
           const float* __restrict__ W_hh,   // [90,30]
           const float* __restrict__ b_ih,   // [90]
           const float* __restrict__ b_hh,   // [90]
           const float* __restrict__ W_out,  // [1,30]
           const float* __restrict__ b_out,  // [1]
           float* __restrict__ out) {
    // Double-buffered h, halves padded to 16 floats for aligned b128 reads.
    __shared__ __align__(16) float hbuf[2][32];
    const int lane = threadIdx.x;
    const int p = lane >> 5;           // which half of the reduction
    const int k = lane & 31;           // hidden unit
    const bool active = (k < HID);
    const int kk = active ? k : (HID - 1);
    const int b = blockIdx.x;
    const int j0 = p * 15;             // my hh column range
    const int d0 = p * 5;              // my ih column range

    // Per-lane weights: 45 hh + 15 ih = 60 VGPRs
    float whh_r[15], whh_z[15], whh_n[15];
#pragma unroll
    for (int jj = 0; jj < 15; ++jj) {
        int j = j0 + jj;
        whh_r[jj] = W_hh[(0 * HID + kk) * HID + j];
        whh_z[jj] = W_hh[(1 * HID + kk) * HID + j];
        whh_n[jj] = W_hh[(2 * HID + kk) * HID + j];
    }
    float wih_r[5], wih_z[5], wih_n[5];
#pragma unroll
    for (int dd = 0; dd < 5; ++dd) {
        int d = d0 + dd;
        wih_r[dd] = W_ih[(0 * HID + kk) * NF + d];
        wih_z[dd] = W_ih[(1 * HID + kk) * NF + d];
        wih_n[dd] = W_ih[(2 * HID + kk) * NF + d];
    }
    const float brz_r = b_ih[0 * HID + kk] + b_hh[0 * HID + kk];
    const float brz_z = b_ih[1 * HID + kk] + b_hh[1 * HID + kk];
    const float bi_n  = b_ih[2 * HID + kk];  // n-gate biases stay split:
    const float bh_n  = b_hh[2 * HID + kk];  // n = tanh(i_n + r*(hh_n + b_hh_n))

    const float* xp = feat + (long)b * FEAT_PER_B + (long)d0 * S3T;

    hbuf[0][lane & 31] = 0.0f;  // zero step-0 read buffer (incl. pad slots)
    __syncthreads();

    float h = 0.0f;
    float xc[5];
#pragma unroll
    for (int dd = 0; dd < 5; ++dd) xc[dd] = xp[dd * S3T];

#pragma unroll 2
    for (int s = 0; s < S3T; ++s) {
        float* rb = hbuf[s & 1];
        float* wb = hbuf[(s + 1) & 1];

        // Prefetch next step's x (stride 6144 B, LLC-resident)
        float xn[5];
        const int sn = (s + 1 < S3T) ? (s + 1) : s;
#pragma unroll
        for (int dd = 0; dd < 5; ++dd) xn[dd] = xp[dd * S3T + sn];

        // h broadcast: 4 x ds_read_b128 (16 floats, 15 used)
        const float4* hv = (const float4*)&rb[p * 16];
        float hj[16];
        *(float4*)&hj[0]  = hv[0];
        *(float4*)&hj[4]  = hv[1];
        *(float4*)&hj[8]  = hv[2];
        *(float4*)&hj[12] = hv[3];

        float ar = 0.0f, az = 0.0f, ani = 0.0f, anh = 0.0f;
#pragma unroll
        for (int dd = 0; dd < 5; ++dd) {
            ar  += wih_r[dd] * xc[dd];
            az  += wih_z[dd] * xc[dd];
            ani += wih_n[dd] * xc[dd];
        }
#pragma unroll
        for (int jj = 0; jj < 15; ++jj) {
            ar  += whh_r[jj] * hj[jj];
            az  += whh_z[jj] * hj[jj];
            anh += whh_n[jj] * hj[jj];
        }
        // combine lane-pair halves (biases added once, after the reduce)
        ar  += __shfl_xor(ar, 32, 64);
        az  += __shfl_xor(az, 32, 64);
        ani += __shfl_xor(ani, 32, 64);
        anh += __shfl_xor(anh, 32, 64);

        float rg = sigmoid_(ar + brz_r);
        float zg = sigmoid_(az + brz_z);
        float ng = tanh_(ani + bi_n + rg * (anh + bh_n));
        h = ng + zg * (h - ng);  // (1-z)*n + z*h

        if (p == 0 && active) wb[(k < 15) ? k : (k + 1)] = h;
        __syncthreads();  // write visible before next step's reads; also
                          // drains this step's rb reads before wb reuse

#pragma unroll
        for (int dd = 0; dd < 5; ++dd) xc[dd] = xn[dd];
    }

    // out[b] = relu(h . W_out + b_out); only p==0,k<30 lanes contribute
    float prod = h * (active ? W_out[kk] : 0.0f);
    float v = (p == 0 && active) ? prod : 0.0f;
#pragma unroll
    for (int off = 32; off; off >>= 1) v += __shfl_xor(v, off, 64);
    if (lane == 0) {
        float o = v + b_out[0];
        out[b] = o > 0.0f ? o : 0.0f;
    }
}

extern "C" void kernel_launch(void* const* d_in, const int* in_sizes, int n_in,
                              void* d_out, int out_size, void* d_ws, size_t ws_size,
                              hipStream_t stream) {
    const int* atom_i   = (const int*)d_in[0];
    const int* atom_j   = (const int*)d_in[1];
    const float* dist   = (const float*)d_in[2];
    const float* emb    = (const float*)d_in[3];
    const float* W_ih   = (const float*)d_in[4];
    const float* W_hh   = (const float*)d_in[5];
    const float* b_ih   = (const float*)d_in[6];
    const float* b_hh   = (const float*)d_in[7];
    const float* W_out  = (const float*)d_in[8];
    const float* b_out  = (const float*)d_in[9];
    float* out = (float*)d_out;
    float* feat = (float*)d_ws;

    const int total = BATCH * FEAT_PER_B;
    const int threads = 256;
    const int blocks = (total + threads - 1) / threads;
    feat_kernel<<<blocks, threads, 0, stream>>>(atom_i, atom_j, dist, emb, feat);
    gru_kernel<<<BATCH, 64, 0, stream>>>(feat, W_ih, W_hh, b_ih, b_hh,
                                         W_out, b_out, out);
}

// Round 7
// 776.299 us; speedup vs baseline: 1.4880x; 1.0644x over previous
//
#include <hip/hip_runtime.h>

// Problem constants (from reference)
#define BATCH 2048
#define T 512
#define NF 10
#define HID 30
#define S3T 1536          // 3*T sequence length after reshape/transpose
#define FEAT_PER_B 15360  // T*30 floats per batch element
// Workspace: BATCH * FEAT_PER_B * 4 = 125,829,120 bytes (fp32 feat)

typedef float v2f __attribute__((ext_vector_type(2)));  // -> v_pk_fma_f32

__device__ __forceinline__ float fexp(float x) {
    return __builtin_amdgcn_exp2f(x * 1.44269504088896f);  // v_exp_f32
}
__device__ __forceinline__ float frcp(float x) {
    return __builtin_amdgcn_rcpf(x);                        // v_rcp_f32
}
__device__ __forceinline__ float sigmoid_(float x) {
    return frcp(1.0f + fexp(-x));
}
__device__ __forceinline__ float tanh_(float x) {
    return 2.0f * frcp(1.0f + fexp(-2.0f * x)) - 1.0f;
}

// Kernel 1: materialize featflat[b][t*30+c] = concat(e_i, e_j, rbf)
__global__ void feat_kernel(const int* __restrict__ atom_i,
                            const int* __restrict__ atom_j,
                            const float* __restrict__ dist,
                            const float* __restrict__ emb,
                            float* __restrict__ feat) {
    int gid = blockIdx.x * blockDim.x + threadIdx.x;
    const int total = BATCH * FEAT_PER_B;
    if (gid >= total) return;
    int b = gid / FEAT_PER_B;
    int r = gid - b * FEAT_PER_B;
    int t = r / 30;
    int c = r - t * 30;
    int bt = b * T + t;
    float v;
    if (c < 10) {
        int ai = atom_i[bt];
        v = (ai != 0) ? emb[ai * NF + c] : 0.0f;
    } else if (c < 20) {
        int aj = atom_j[bt];
        v = (aj != 0) ? emb[aj * NF + (c - 10)] : 0.0f;
    } else {
        int ai = atom_i[bt];
        float d = dist[bt];
        float ctr = (float)(c - 19) * 0.7f;
        float diff = ctr - d;
        v = (ai != 0) ? fexp(-diff * diff) : 0.0f;
    }
    feat[gid] = v;
}

// Kernel 2: GRU recurrence. One wave per block, one batch element per wave.
// Lane pair (k, k+32) shares hidden unit k: half p accumulates 15(+1 pad) of
// the 30 hh terms (as 8 v_pk_fma_f32) and 5 of the 10 ih terms; one
// shfl_xor(32) combines.
//
// amdgpu_waves_per_eu(2,2) [R6: VGPR 52->88, 926->768us]: sets the occupancy
// CEILING so the scheduler's pressure target matches the 2 waves/SIMD the
// 2048-wave grid actually supplies; without it LLVM shrinks to 52 VGPRs for
// unreachable 8-wave occupancy and AGPR-bounces the weights every step.
__attribute__((amdgpu_waves_per_eu(2, 2)))
__global__ void __launch_bounds__(64)
gru_kernel(const float* __restrict__ feat,
           const float* __restrict__ W_ih,   // [90,10]
           const float* __restrict__ W_hh,   // [90,30]
           const float* __restrict__ b_ih,   // [90]
           const float* __restrict__ b_hh,   // [90]
           const float* __restrict__ W_out,  // [1,30]
           const float* __restrict__ b_out,  // [1]
           float* __restrict__ out) {
    // Double-buffered h, halves padded to 16 floats for aligned b128 reads.
    // Pad slots (15, 31) of BOTH buffers are zeroed at init and never written
    // again -> the 16th pk lane multiplies 0 (never the 0xAA poison).
    __shared__ __align__(16) float hbuf[2][32];
    const int lane = threadIdx.x;
    const int p = lane >> 5;           // which half of the reduction
    const int k = lane & 31;           // hidden unit
    const bool active = (k < HID);
    const int kk = active ? k : (HID - 1);
    const int b = blockIdx.x;
    const int j0 = p * 15;             // my hh column range
    const int d0 = p * 5;              // my ih column range

    // Per-lane hh weights as 8 j-pairs per gate (16th element zero-padded).
    v2f whh_r[8], whh_z[8], whh_n[8];
#pragma unroll
    for (int jj = 0; jj < 8; ++jj) {
        int j = j0 + 2 * jj;
        float r0 = W_hh[(0 * HID + kk) * HID + j];
        float z0 = W_hh[(1 * HID + kk) * HID + j];
        float n0 = W_hh[(2 * HID + kk) * HID + j];
        float r1 = 0.0f, z1 = 0.0f, n1 = 0.0f;
        if (jj < 7) {  // pair 7's second lane is the pad (j0+15)
            r1 = W_hh[(0 * HID + kk) * HID + j + 1];
            z1 = W_hh[(1 * HID + kk) * HID + j + 1];
            n1 = W_hh[(2 * HID + kk) * HID + j + 1];
        }
        whh_r[jj] = (v2f){r0, r1};
        whh_z[jj] = (v2f){z0, z1};
        whh_n[jj] = (v2f){n0, n1};
    }
    float wih_r[5], wih_z[5], wih_n[5];
#pragma unroll
    for (int dd = 0; dd < 5; ++dd) {
        int d = d0 + dd;
        wih_r[dd] = W_ih[(0 * HID + kk) * NF + d];
        wih_z[dd] = W_ih[(1 * HID + kk) * NF + d];
        wih_n[dd] = W_ih[(2 * HID + kk) * NF + d];
    }
    // Biases folded into accumulator init on the p==0 half only (they must
    // appear exactly once in the cross-half shfl sum).
    const float bini_r = (p == 0) ? b_ih[0 * HID + kk] + b_hh[0 * HID + kk] : 0.0f;
    const float bini_z = (p == 0) ? b_ih[1 * HID + kk] + b_hh[1 * HID + kk] : 0.0f;
    const float bini_i = (p == 0) ? b_ih[2 * HID + kk] : 0.0f;  // n stays split:
    const float bini_h = (p == 0) ? b_hh[2 * HID + kk] : 0.0f;  // n=tanh(i_n+r*hh_n')

    const float* xp = feat + (long)b * FEAT_PER_B + (long)d0 * S3T;

    hbuf[0][lane & 31] = 0.0f;  // zero step-0 read buffer (incl. pads)
    hbuf[1][lane & 31] = 0.0f;  // zero buffer-1 pads (units get overwritten)
    __syncthreads();

    float h = 0.0f;
    float xc[5];
#pragma unroll
    for (int dd = 0; dd < 5; ++dd) xc[dd] = xp[dd * S3T];

#pragma unroll 2
    for (int s = 0; s < S3T; ++s) {
        float* rb = hbuf[s & 1];
        float* wb = hbuf[(s + 1) & 1];

        // Prefetch next step's x (stride 6144 B, LLC-resident)
        float xn[5];
        const int sn = (s + 1 < S3T) ? (s + 1) : s;
#pragma unroll
        for (int dd = 0; dd < 5; ++dd) xn[dd] = xp[dd * S3T + sn];

        // h broadcast: 4 x ds_read_b128 -> 8 v2f pairs (16th elem = 0 pad)
        const float4* hv = (const float4*)&rb[p * 16];
        float4 q0 = hv[0], q1 = hv[1], q2 = hv[2], q3 = hv[3];
        v2f hj2[8];
        hj2[0] = (v2f){q0.x, q0.y}; hj2[1] = (v2f){q0.z, q0.w};
        hj2[2] = (v2f){q1.x, q1.y}; hj2[3] = (v2f){q1.z, q1.w};
        hj2[4] = (v2f){q2.x, q2.y}; hj2[5] = (v2f){q2.z, q2.w};
        hj2[6] = (v2f){q3.x, q3.y}; hj2[7] = (v2f){q3.z, q3.w};

        // hh dot products: 8 v_pk_fma_f32 per gate
        v2f ar2 = (v2f){bini_r, 0.0f};
        v2f az2 = (v2f){bini_z, 0.0f};
        v2f anh2 = (v2f){bini_h, 0.0f};
#pragma unroll
        for (int jj = 0; jj < 8; ++jj) {
            ar2  += whh_r[jj] * hj2[jj];
            az2  += whh_z[jj] * hj2[jj];
            anh2 += whh_n[jj] * hj2[jj];
        }
        // ih dot products (scalar, 15 FMA)
        float ani = bini_i;
        float ar = ar2.x + ar2.y;
        float az = az2.x + az2.y;
        float anh = anh2.x + anh2.y;
#pragma unroll
        for (int dd = 0; dd < 5; ++dd) {
            ar  += wih_r[dd] * xc[dd];
            az  += wih_z[dd] * xc[dd];
            ani += wih_n[dd] * xc[dd];
        }
        // combine lane-pair halves (biases already in p==0's init)
        ar  += __shfl_xor(ar, 32, 64);
        az  += __shfl_xor(az, 32, 64);
        ani += __shfl_xor(ani, 32, 64);
        anh += __shfl_xor(anh, 32, 64);

        float rg = sigmoid_(ar);
        float zg = sigmoid_(az);
        float ng = tanh_(ani + rg * anh);
        h = ng + zg * (h - ng);  // (1-z)*n + z*h

        if (p == 0 && active) wb[(k < 15) ? k : (k + 1)] = h;
        __syncthreads();  // write visible before next step's reads; also
                          // drains this step's rb reads before wb reuse

#pragma unroll
        for (int dd = 0; dd < 5; ++dd) xc[dd] = xn[dd];
    }

    // out[b] = relu(h . W_out + b_out); only p==0,k<30 lanes contribute
    float prod = h * (active ? W_out[kk] : 0.0f);
    float v = (p == 0 && active) ? prod : 0.0f;
#pragma unroll
    for (int off = 32; off; off >>= 1) v += __shfl_xor(v, off, 64);
    if (lane == 0) {
        float o = v + b_out[0];
        out[b] = o > 0.0f ? o : 0.0f;
    }
}

extern "C" void kernel_launch(void* const* d_in, const int* in_sizes, int n_in,
                              void* d_out, int out_size, void* d_ws, size_t ws_size,
                              hipStream_t stream) {
    const int* atom_i   = (const int*)d_in[0];
    const int* atom_j   = (const int*)d_in[1];
    const float* dist   = (const float*)d_in[2];
    const float* emb    = (const float*)d_in[3];
    const float* W_ih   = (const float*)d_in[4];
    const float* W_hh   = (const float*)d_in[5];
    const float* b_ih   = (const float*)d_in[6];
    const float* b_hh   = (const float*)d_in[7];
    const float* W_out  = (const float*)d_in[8];
    const float* b_out  = (const float*)d_in[9];
    float* out = (float*)d_out;
    float* feat = (float*)d_ws;

    const int total = BATCH * FEAT_PER_B;
    const int threads = 256;
    const int blocks = (total + threads - 1) / threads;
    feat_kernel<<<blocks, threads, 0, stream>>>(atom_i, atom_j, dist, emb, feat);
    gru_kernel<<<BATCH, 64, 0, stream>>>(feat, W_ih, W_hh, b_ih, b_hh,
                                         W_out, b_out, out);
}